// Round 13
// baseline (107.872 us; speedup 1.0000x reference)
//
#include <hip/hip_runtime.h>
#include <hip/hip_bf16.h>

#define B_ 8
#define W_ 128
#define K_ 2048
#define D_ 256
#define WX 144            // padded w-dim: 128 x-cols + E1-col(128) + 15 zero cols
#define NC 256            // K/8 j-chunks

typedef __attribute__((ext_vector_type(8))) short bf16x8;
typedef __attribute__((ext_vector_type(4))) float f32x4;

static __device__ __forceinline__ short f2bf(float f) {
    unsigned int u = __float_as_uint(f);
    unsigned int r = (u + 0x7FFFu + ((u >> 16) & 1u)) >> 16;
    return (short)r;
}

// ---------- k_w2v: w2v[w] = sum_d W_lin[W+w][d] * a[d]  (128 blocks x 1 wave)
__global__ void k_w2v(const float* __restrict__ W_lin, const float* __restrict__ a,
                      float* __restrict__ w2v) {
    int w = blockIdx.x, l = threadIdx.x;
    float4 rv = ((const float4*)(W_lin + (size_t)(W_ + w) * D_))[l];
    float4 av = ((const float4*)a)[l];
    float acc = rv.x * av.x + rv.y * av.y + rv.z * av.z + rv.w * av.w;
    for (int m = 1; m < 64; m <<= 1) acc += __shfl_xor(acc, m);
    if (l == 0) w2v[w] = acc;
}

// ---------- k_pe: heterogeneous grid (768 blocks x 512 thr)  [proven, unchanged]
__global__ __launch_bounds__(512) void k_pe(const float* __restrict__ x,
        const float* __restrict__ w2v, const float* __restrict__ bias,
        short* __restrict__ xbt, short* __restrict__ e2t) {
    __shared__ float sc[696];
    int tid = threadIdx.x;
    int wid = tid >> 6;
    int lane = tid & 63;

    if (blockIdx.x < 512) {
        // ---- prep: this block owns 32 k-cols ----
        if (tid < W_) sc[tid] = w2v[tid];          // ws
        __syncthreads();
        int q = tid & 31, cw = tid >> 5;           // cw 0..15, 8 w each
        int bk0 = blockIdx.x * 32;
        int b = bk0 >> 11;
        int k = (bk0 & (K_ - 1)) + q;
        const float* xp = x + ((size_t)b * W_ + cw * 8) * K_ + k;
        float xv[8];
        float acc = 0.f;
#pragma unroll
        for (int w = 0; w < 8; ++w) {
            xv[w] = xp[(size_t)w * K_];
            acc += xv[w] * sc[cw * 8 + w];
        }
        sc[128 + cw * 33 + q] = acc;               // red[16][33]
        __syncthreads();
        if (tid < 32) {
            float s = 0.f;
#pragma unroll
            for (int cc = 0; cc < 16; ++cc) s += sc[128 + cc * 33 + tid];
            sc[656 + tid] = __expf(s);             // e1s; |u2| small, shift-invariant
        }
        __syncthreads();
        float e1q = sc[656 + q];
        short* xo = xbt + (((size_t)b * NC + (k >> 3)) * WX + cw * 8) * 8 + (k & 7);
#pragma unroll
        for (int w = 0; w < 8; ++w) xo[w * 8] = f2bf(xv[w] * e1q);
        if (tid < 32) {   // E1 column (w=128)
            int kk = (bk0 & (K_ - 1)) + tid;
            xbt[(((size_t)b * NC + (kk >> 3)) * WX + 128) * 8 + (kk & 7)] = f2bf(sc[656 + tid]);
        }
        if (tid >= 64 && tid < 124) {   // zero cols 129..143, this block's 4 c-chunks
            int id = tid - 64;
            int cl = id / 15, wz = 129 + id % 15;
            int c = ((bk0 & (K_ - 1)) >> 3) + cl;
            bf16x8 z = {0, 0, 0, 0, 0, 0, 0, 0};
            *(bf16x8*)(xbt + (((size_t)b * NC + c) * WX + wz) * 8) = z;
        }
    } else {
        // ---- e2: 8 rows per block (256 blocks), 64-B write runs ----
        int i0e = (blockIdx.x - 512) * 8;
        {
            const float4* bp = (const float4*)(bias + (size_t)(i0e + wid) * K_);
            float m = -1e30f;
#pragma unroll
            for (int s = 0; s < 8; ++s) {
                float4 v = bp[lane + s * 64];
                m = fmaxf(m, fmaxf(fmaxf(v.x, v.y), fmaxf(v.z, v.w)));
            }
#pragma unroll
            for (int mm = 1; mm < 64; mm <<= 1) m = fmaxf(m, __shfl_xor(m, mm));
            if (lane == 0) sc[wid] = m;
        }
        __syncthreads();
        {
            int ilr = tid & 7, cg = tid >> 3;      // cg 0..63, 4 c-chunks each
            float mb = sc[ilr];
            int i = i0e + ilr;
            const float4* brow = (const float4*)(bias + (size_t)i * K_);
#pragma unroll
            for (int it = 0; it < 4; ++it) {
                int c = cg * 4 + it;
                float4 v0 = brow[c * 2];
                float4 v1 = brow[c * 2 + 1];
                bf16x8 o;
                o[0] = f2bf(__expf(v0.x - mb)); o[1] = f2bf(__expf(v0.y - mb));
                o[2] = f2bf(__expf(v0.z - mb)); o[3] = f2bf(__expf(v0.w - mb));
                o[4] = f2bf(__expf(v1.x - mb)); o[5] = f2bf(__expf(v1.y - mb));
                o[6] = f2bf(__expf(v1.z - mb)); o[7] = f2bf(__expf(v1.w - mb));
                *(bf16x8*)(e2t + ((size_t)c * K_ + i) * 8) = o;
            }
        }
    }
}

// ---------- k_gemm: D[b,i,wcol] = sum_j E2[i,j]*X'[b,wcol,j]; col 128 = l.
// grid 256 = 32 i-tiles (64 rows) x 8 b. b = blk&7 -> XCD-pinned, B slice (576KB)
// L2-resident. 8 waves = 4 m-tiles (m=wid&3, 16 rows each) x 2 j-halves (js=wid>>2,
// 1024 j). The 4 m-waves of a j-half read IDENTICAL B addresses -> L1 dedup ->
// distinct B per block = 576KB covering 64 rows (2x better than r8, 4x than r12).
// acc = 9 f32x4 = 36 VGPR; grid=1 block/CU so VGPR>128 free -> launch_bounds(512,2)
// + depth-1 full-set prefetch (~116 VGPR). 2-way LDS reduce, direct global stores.
struct SetF { bf16x8 A; bf16x8 B0, B1, B2, B3, B4, B5, B6, B7, B8; };

#define MF(a_, b_, c_) __builtin_amdgcn_mfma_f32_16x16x32_bf16(a_, b_, c_, 0, 0, 0)

#define FETCHF(S, c_) do {                                         \
    const short* _e = eA + (size_t)(c_) * (K_ * 8);                \
    const short* _x = xB + (size_t)(c_) * (WX * 8);                \
    S.A  = *(const bf16x8*)(_e);                                   \
    S.B0 = *(const bf16x8*)(_x);                                   \
    S.B1 = *(const bf16x8*)(_x + 128);                             \
    S.B2 = *(const bf16x8*)(_x + 256);                             \
    S.B3 = *(const bf16x8*)(_x + 384);                             \
    S.B4 = *(const bf16x8*)(_x + 512);                             \
    S.B5 = *(const bf16x8*)(_x + 640);                             \
    S.B6 = *(const bf16x8*)(_x + 768);                             \
    S.B7 = *(const bf16x8*)(_x + 896);                             \
    S.B8 = *(const bf16x8*)(_x + 1024);                            \
} while (0)

#define CONSUMEF(S) do {                                           \
    q0 = MF(S.A, S.B0, q0); q1 = MF(S.A, S.B1, q1);                \
    q2 = MF(S.A, S.B2, q2); q3 = MF(S.A, S.B3, q3);                \
    q4 = MF(S.A, S.B4, q4); q5 = MF(S.A, S.B5, q5);                \
    q6 = MF(S.A, S.B6, q6); q7 = MF(S.A, S.B7, q7);                \
    q8 = MF(S.A, S.B8, q8);                                        \
} while (0)

__global__ __launch_bounds__(512, 2) void k_gemm(const short* __restrict__ e2t,
        const short* __restrict__ xbt, float* __restrict__ out) {
    __shared__ f32x4 slots[4][9][64];    // 36 KB, lane-contiguous -> conflict-free
    int blk  = blockIdx.x;
    int b    = blk & 7;                  // XCD round-robin -> same b per XCD
    int i0   = (blk >> 3) * 64;
    int tid  = threadIdx.x;
    int wid  = tid >> 6;
    int lane = tid & 63;
    int il   = lane & 15;
    int kg   = lane >> 4;
    int m    = wid & 3;                  // m-tile: rows i0+m*16 .. +15
    int js   = wid >> 2;                 // j-half: 1024 j

    const short* eA = e2t + (((size_t)(js * 128 + kg)) * K_ + i0 + m * 16 + il) * 8;
    const short* xB = xbt + (((size_t)b * NC + js * 128 + kg) * WX + il) * 8;

    f32x4 q0{0,0,0,0}, q1{0,0,0,0}, q2{0,0,0,0}, q3{0,0,0,0}, q4{0,0,0,0},
          q5{0,0,0,0}, q6{0,0,0,0}, q7{0,0,0,0}, q8{0,0,0,0};

    SetF X, Y;
    FETCHF(X, 0);
    for (int s = 0; s < 32; s += 2) {    // 32 k-steps x 32 j = 1024 j
        FETCHF(Y, (s + 1) * 4);
        CONSUMEF(X);
        if (s + 2 < 32) FETCHF(X, (s + 2) * 4);
        CONSUMEF(Y);
    }

    // 2-way reduce over j-halves: js=1 dumps, js=0 gathers
    if (js == 1) {
        slots[m][0][lane] = q0; slots[m][1][lane] = q1; slots[m][2][lane] = q2;
        slots[m][3][lane] = q3; slots[m][4][lane] = q4; slots[m][5][lane] = q5;
        slots[m][6][lane] = q6; slots[m][7][lane] = q7; slots[m][8][lane] = q8;
    }
    __syncthreads();
    if (js == 0) {
        q0 += slots[m][0][lane]; q1 += slots[m][1][lane]; q2 += slots[m][2][lane];
        q3 += slots[m][3][lane]; q4 += slots[m][4][lane]; q5 += slots[m][5][lane];
        q6 += slots[m][6][lane]; q7 += slots[m][7][lane]; q8 += slots[m][8][lane];

        // l for rows kg*4+r lives in q8[r] at lane kg*16 (w=128 column)
        float linv0 = 1.f / __shfl(q8[0], kg * 16);
        float linv1 = 1.f / __shfl(q8[1], kg * 16);
        float linv2 = 1.f / __shfl(q8[2], kg * 16);
        float linv3 = 1.f / __shfl(q8[3], kg * 16);

        float* ob = out + (size_t)b * W_ * K_ + i0 + m * 16 + kg * 4;
#define STQ(n_, q_) do {                                            \
        float4 o;                                                   \
        o.x = 1.f / (1.f + __expf(-q_[0] * linv0));                 \
        o.y = 1.f / (1.f + __expf(-q_[1] * linv1));                 \
        o.z = 1.f / (1.f + __expf(-q_[2] * linv2));                 \
        o.w = 1.f / (1.f + __expf(-q_[3] * linv3));                 \
        *(float4*)(ob + (size_t)((n_) * 16 + il) * K_) = o; } while (0)
        STQ(0, q0); STQ(1, q1); STQ(2, q2); STQ(3, q3);
        STQ(4, q4); STQ(5, q5); STQ(6, q6); STQ(7, q7);
#undef STQ
    }
}

extern "C" void kernel_launch(void* const* d_in, const int* in_sizes, int n_in,
                              void* d_out, int out_size, void* d_ws, size_t ws_size,
                              hipStream_t stream) {
    const float* x     = (const float*)d_in[0];
    const float* W_lin = (const float*)d_in[1];
    // d_in[2] = b_lin: constant along softmax axis -> cancels, unused
    const float* a     = (const float*)d_in[3];
    const float* bias  = (const float*)d_in[4];
    float* out = (float*)d_out;

    float* w2v = (float*)d_ws;                    // 128 f32
    short* xbt = (short*)(w2v + 128);             // 8*256*144*8 bf16 = 4.72 MB
    short* e2t = xbt + (size_t)B_ * NC * WX * 8;  // 256*2048*8 bf16 = 8 MB

    k_w2v <<<128, 64, 0, stream>>>(W_lin, a, w2v);
    k_pe  <<<768, 512, 0, stream>>>(x, w2v, bias, xbt, e2t);
    k_gemm<<<256, 512, 0, stream>>>(e2t, xbt, out);
}

// Round 14
// 40.085 us; speedup vs baseline: 2.6911x; 2.6911x over previous
//
#include <hip/hip_runtime.h>
#include <hip/hip_bf16.h>

#define B_ 8
#define W_ 128
#define K_ 2048
#define D_ 256
#define WX 144            // padded w-dim: 128 x-cols + E1-col(128) + 15 zero cols
#define NC 256            // K/8 j-chunks

typedef __attribute__((ext_vector_type(8))) short bf16x8;
typedef __attribute__((ext_vector_type(4))) float f32x4;

static __device__ __forceinline__ short f2bf(float f) {
    unsigned int u = __float_as_uint(f);
    unsigned int r = (u + 0x7FFFu + ((u >> 16) & 1u)) >> 16;
    return (short)r;
}

// ---------- k_w2v: w2v[w] = sum_d W_lin[W+w][d] * a[d]  (128 blocks x 1 wave)
__global__ void k_w2v(const float* __restrict__ W_lin, const float* __restrict__ a,
                      float* __restrict__ w2v) {
    int w = blockIdx.x, l = threadIdx.x;
    float4 rv = ((const float4*)(W_lin + (size_t)(W_ + w) * D_))[l];
    float4 av = ((const float4*)a)[l];
    float acc = rv.x * av.x + rv.y * av.y + rv.z * av.z + rv.w * av.w;
    for (int m = 1; m < 64; m <<= 1) acc += __shfl_xor(acc, m);
    if (l == 0) w2v[w] = acc;
}

// ---------- k_pe: heterogeneous grid (1024 blocks x 512 thr) — r10's proven shape
// blocks 0..511   : prep -> u2 reduce, E1=exp(u2), xbt = bf16(x*E1) blocked (+E1 col)
// blocks 512..1023: e2   -> E2 = bf16(exp(bias-rowmax)), 4 rows/block
__global__ __launch_bounds__(512) void k_pe(const float* __restrict__ x,
        const float* __restrict__ w2v, const float* __restrict__ bias,
        short* __restrict__ xbt, short* __restrict__ e2t) {
    __shared__ float sc[696];
    int tid = threadIdx.x;
    int wid = tid >> 6;
    int lane = tid & 63;

    if (blockIdx.x < 512) {
        // ---- prep: this block owns 32 k-cols ----
        if (tid < W_) sc[tid] = w2v[tid];          // ws
        __syncthreads();
        int q = tid & 31, cw = tid >> 5;           // cw 0..15, 8 w each
        int bk0 = blockIdx.x * 32;
        int b = bk0 >> 11;
        int k = (bk0 & (K_ - 1)) + q;
        const float* xp = x + ((size_t)b * W_ + cw * 8) * K_ + k;
        float xv[8];
        float acc = 0.f;
#pragma unroll
        for (int w = 0; w < 8; ++w) {
            xv[w] = xp[(size_t)w * K_];
            acc += xv[w] * sc[cw * 8 + w];
        }
        sc[128 + cw * 33 + q] = acc;               // red[16][33]
        __syncthreads();
        if (tid < 32) {
            float s = 0.f;
#pragma unroll
            for (int cc = 0; cc < 16; ++cc) s += sc[128 + cc * 33 + tid];
            sc[656 + tid] = __expf(s);             // e1s; |u2| small, shift-invariant
        }
        __syncthreads();
        float e1q = sc[656 + q];
        short* xo = xbt + (((size_t)b * NC + (k >> 3)) * WX + cw * 8) * 8 + (k & 7);
#pragma unroll
        for (int w = 0; w < 8; ++w) xo[w * 8] = f2bf(xv[w] * e1q);
        if (tid < 32) {   // E1 column (w=128)
            int kk = (bk0 & (K_ - 1)) + tid;
            xbt[(((size_t)b * NC + (kk >> 3)) * WX + 128) * 8 + (kk & 7)] = f2bf(sc[656 + tid]);
        }
        if (tid >= 64 && tid < 124) {   // zero cols 129..143, this block's 4 c-chunks
            int id = tid - 64;
            int cl = id / 15, wz = 129 + id % 15;
            int c = ((bk0 & (K_ - 1)) >> 3) + cl;
            bf16x8 z = {0, 0, 0, 0, 0, 0, 0, 0};
            *(bf16x8*)(xbt + (((size_t)b * NC + c) * WX + wz) * 8) = z;
        }
    } else {
        // ---- e2: 4 rows per block (512 blocks) ----
        int i0e = (int)(blockIdx.x - 512) * 4;
        {
            int r = tid >> 7, t128 = tid & 127;    // 4 rows x 128 thr (2 waves/row)
            const float4* bp = (const float4*)(bias + (size_t)(i0e + r) * K_);
            float m = -1e30f;
#pragma unroll
            for (int s = 0; s < 4; ++s) {
                float4 v = bp[t128 + s * 128];
                m = fmaxf(m, fmaxf(fmaxf(v.x, v.y), fmaxf(v.z, v.w)));
            }
#pragma unroll
            for (int mm = 1; mm < 64; mm <<= 1) m = fmaxf(m, __shfl_xor(m, mm));
            if (lane == 0) sc[wid] = m;            // 8 per-wave maxes (2 per row)
        }
        __syncthreads();
        {
            int il = tid & 3, cg_ = tid >> 2;       // cg_ 0..127, 2 c-chunks each
            float mb = fmaxf(sc[il * 2], sc[il * 2 + 1]);
            int i = i0e + il;
            const float4* brow = (const float4*)(bias + (size_t)i * K_);
#pragma unroll
            for (int it = 0; it < 2; ++it) {
                int c = cg_ * 2 + it;
                float4 v0 = brow[c * 2];
                float4 v1 = brow[c * 2 + 1];
                bf16x8 o;
                o[0] = f2bf(__expf(v0.x - mb)); o[1] = f2bf(__expf(v0.y - mb));
                o[2] = f2bf(__expf(v0.z - mb)); o[3] = f2bf(__expf(v0.w - mb));
                o[4] = f2bf(__expf(v1.x - mb)); o[5] = f2bf(__expf(v1.y - mb));
                o[6] = f2bf(__expf(v1.z - mb)); o[7] = f2bf(__expf(v1.w - mb));
                *(bf16x8*)(e2t + ((size_t)c * K_ + i) * 8) = o;
            }
        }
    }
}

// ---------- k_gemm: r8/r10 proven structure + s_setprio around MFMA cluster.
// grid 512: b = blk&7 (XCD-local), i0 = (blk>>3)*32. 8 waves = 8 independent
// j-slices (256 j each); wave = 2 m-tiles x 9 n. launch_bounds(512,4) -> VGPR<=128,
// 2 blocks/CU = 4 waves/SIMD. No barriers in main loop -> waves phase-drift,
// the regime where setprio(1) on MFMA pays (T5 attn-like case).
struct SetG {
    bf16x8 A0, A1;
    bf16x8 B0, B1, B2, B3, B4, B5, B6, B7, B8;
};

#define FETCHG(S, c_) do {                                         \
    const short* _e = eA + (size_t)(c_) * (K_ * 8);                \
    const short* _x = xB + (size_t)(c_) * (WX * 8);                \
    S.A0 = *(const bf16x8*)(_e);                                   \
    S.A1 = *(const bf16x8*)(_e + 128);                             \
    S.B0 = *(const bf16x8*)(_x);                                   \
    S.B1 = *(const bf16x8*)(_x + 128);                             \
    S.B2 = *(const bf16x8*)(_x + 256);                             \
    S.B3 = *(const bf16x8*)(_x + 384);                             \
    S.B4 = *(const bf16x8*)(_x + 512);                             \
    S.B5 = *(const bf16x8*)(_x + 640);                             \
    S.B6 = *(const bf16x8*)(_x + 768);                             \
    S.B7 = *(const bf16x8*)(_x + 896);                             \
    S.B8 = *(const bf16x8*)(_x + 1024);                            \
} while (0)

#define MF(a_, b_, c_) __builtin_amdgcn_mfma_f32_16x16x32_bf16(a_, b_, c_, 0, 0, 0)

#define CONSUMEG(S) do {                                           \
    __builtin_amdgcn_s_setprio(1);                                 \
    acc0[0] = MF(S.A0, S.B0, acc0[0]); acc1[0] = MF(S.A1, S.B0, acc1[0]); \
    acc0[1] = MF(S.A0, S.B1, acc0[1]); acc1[1] = MF(S.A1, S.B1, acc1[1]); \
    acc0[2] = MF(S.A0, S.B2, acc0[2]); acc1[2] = MF(S.A1, S.B2, acc1[2]); \
    acc0[3] = MF(S.A0, S.B3, acc0[3]); acc1[3] = MF(S.A1, S.B3, acc1[3]); \
    acc0[4] = MF(S.A0, S.B4, acc0[4]); acc1[4] = MF(S.A1, S.B4, acc1[4]); \
    acc0[5] = MF(S.A0, S.B5, acc0[5]); acc1[5] = MF(S.A1, S.B5, acc1[5]); \
    acc0[6] = MF(S.A0, S.B6, acc0[6]); acc1[6] = MF(S.A1, S.B6, acc1[6]); \
    acc0[7] = MF(S.A0, S.B7, acc0[7]); acc1[7] = MF(S.A1, S.B7, acc1[7]); \
    acc0[8] = MF(S.A0, S.B8, acc0[8]); acc1[8] = MF(S.A1, S.B8, acc1[8]); \
    __builtin_amdgcn_s_setprio(0);                                 \
} while (0)

__global__ __launch_bounds__(512, 4) void k_gemm(const short* __restrict__ e2t,
        const short* __restrict__ xbt, float* __restrict__ out) {
    __shared__ f32x4 Rbuf[4][18][64];   // 72 KB; reused as [144][36] f32 epilogue
    int blk  = blockIdx.x;
    int b    = blk & 7;                  // XCD round-robin -> same b per XCD
    int i0   = (blk >> 3) * 32;
    int tid  = threadIdx.x;
    int wid  = tid >> 6;
    int lane = tid & 63;
    int il   = lane & 15;
    int kg   = lane >> 4;

    const short* eA = e2t + ((size_t)kg * K_ + i0 + il) * 8;
    const short* xB = xbt + (((size_t)b * NC + kg) * WX + il) * 8;

    f32x4 acc0[9], acc1[9];
#pragma unroll
    for (int n = 0; n < 9; ++n) { acc0[n] = (f32x4){0,0,0,0}; acc1[n] = (f32x4){0,0,0,0}; }

    SetG X;
    int c0 = wid * 32;                  // 32 c-chunks = 256 j per wave, 8 k-steps
    for (int s = 0; s < 8; ++s) {
        FETCHG(X, c0 + s * 4);
        CONSUMEG(X);
    }

    // 3-stage cross-wave tree reduction (8 -> 4 -> 2 -> 1)
    f32x4* R = (f32x4*)Rbuf;
#define DUMPG(slot) do {                                            \
    _Pragma("unroll") for (int n = 0; n < 9; ++n) {                 \
        R[((slot) * 18 + n) * 64 + lane] = acc0[n];                 \
        R[((slot) * 18 + 9 + n) * 64 + lane] = acc1[n]; } } while (0)
#define GATHG(slot) do {                                            \
    _Pragma("unroll") for (int n = 0; n < 9; ++n) {                 \
        acc0[n] += R[((slot) * 18 + n) * 64 + lane];                \
        acc1[n] += R[((slot) * 18 + 9 + n) * 64 + lane]; } } while (0)

    if (wid >= 4) DUMPG(wid - 4);
    __syncthreads();
    if (wid < 4) GATHG(wid);
    __syncthreads();
    if (wid == 2 || wid == 3) DUMPG(wid - 2);
    __syncthreads();
    if (wid < 2) GATHG(wid);
    __syncthreads();
    if (wid == 1) DUMPG(0);
    __syncthreads();
    if (wid == 0) {
        GATHG(0);
        float* arr = (float*)Rbuf;   // [col 144][36 padded rows]
#pragma unroll
        for (int n = 0; n < 9; ++n) {
            *(f32x4*)(arr + (n * 16 + il) * 36 + kg * 4)      = acc0[n];
            *(f32x4*)(arr + (n * 16 + il) * 36 + 16 + kg * 4) = acc1[n];
        }
    }
    __syncthreads();

    // epilogue: col = tid>>2 (0..127), rows rs..rs+7; l in col 128
    {
        float* arr = (float*)Rbuf;
        int col = tid >> 2;
        int rs  = (tid & 3) * 8;
        f32x4 n0 = *(f32x4*)(arr + col * 36 + rs);
        f32x4 n1 = *(f32x4*)(arr + col * 36 + rs + 4);
        f32x4 l0 = *(f32x4*)(arr + 128 * 36 + rs);
        f32x4 l1 = *(f32x4*)(arr + 128 * 36 + rs + 4);
        float4 o0, o1;
        o0.x = 1.f / (1.f + __expf(-n0[0] / l0[0]));
        o0.y = 1.f / (1.f + __expf(-n0[1] / l0[1]));
        o0.z = 1.f / (1.f + __expf(-n0[2] / l0[2]));
        o0.w = 1.f / (1.f + __expf(-n0[3] / l0[3]));
        o1.x = 1.f / (1.f + __expf(-n1[0] / l1[0]));
        o1.y = 1.f / (1.f + __expf(-n1[1] / l1[1]));
        o1.z = 1.f / (1.f + __expf(-n1[2] / l1[2]));
        o1.w = 1.f / (1.f + __expf(-n1[3] / l1[3]));
        float* op = out + ((size_t)b * W_ + col) * K_ + i0 + rs;
        *(float4*)op = o0;
        *(float4*)(op + 4) = o1;
    }
}

extern "C" void kernel_launch(void* const* d_in, const int* in_sizes, int n_in,
                              void* d_out, int out_size, void* d_ws, size_t ws_size,
                              hipStream_t stream) {
    const float* x     = (const float*)d_in[0];
    const float* W_lin = (const float*)d_in[1];
    // d_in[2] = b_lin: constant along softmax axis -> cancels, unused
    const float* a     = (const float*)d_in[3];
    const float* bias  = (const float*)d_in[4];
    float* out = (float*)d_out;

    float* w2v = (float*)d_ws;                    // 128 f32
    short* xbt = (short*)(w2v + 128);             // 8*256*144*8 bf16 = 4.72 MB
    short* e2t = xbt + (size_t)B_ * NC * WX * 8;  // 256*2048*8 bf16 = 8 MB

    k_w2v <<<128, 64, 0, stream>>>(W_lin, a, w2v);
    k_pe  <<<1024, 512, 0, stream>>>(x, w2v, bias, xbt, e2t);
    k_gemm<<<512, 512, 0, stream>>>(e2t, xbt, out);
}

// Round 15
// 39.797 us; speedup vs baseline: 2.7105x; 1.0072x over previous
//
#include <hip/hip_runtime.h>
#include <hip/hip_bf16.h>

#define B_ 8
#define W_ 128
#define K_ 2048
#define D_ 256
#define WX 144            // padded w-dim: 128 x-cols + E1-col(128) + 15 zero cols
#define NC 256            // K/8 j-chunks

typedef __attribute__((ext_vector_type(8))) short bf16x8;
typedef __attribute__((ext_vector_type(4))) float f32x4;
typedef unsigned int u32;

static __device__ __forceinline__ short f2bf(float f) {
    unsigned int u = __float_as_uint(f);
    unsigned int r = (u + 0x7FFFu + ((u >> 16) & 1u)) >> 16;
    return (short)r;
}

// ---------- k_w2v ----------
__global__ void k_w2v(const float* __restrict__ W_lin, const float* __restrict__ a,
                      float* __restrict__ w2v) {
    int w = blockIdx.x, l = threadIdx.x;
    float4 rv = ((const float4*)(W_lin + (size_t)(W_ + w) * D_))[l];
    float4 av = ((const float4*)a)[l];
    float acc = rv.x * av.x + rv.y * av.y + rv.z * av.z + rv.w * av.w;
    for (int m = 1; m < 64; m <<= 1) acc += __shfl_xor(acc, m);
    if (l == 0) w2v[w] = acc;
}

// ---------- k_pe: heterogeneous grid (1024 blocks x 512 thr) [r14 proven, unchanged]
__global__ __launch_bounds__(512) void k_pe(const float* __restrict__ x,
        const float* __restrict__ w2v, const float* __restrict__ bias,
        short* __restrict__ xbt, short* __restrict__ e2t) {
    __shared__ float sc[696];
    int tid = threadIdx.x;
    int wid = tid >> 6;
    int lane = tid & 63;

    if (blockIdx.x < 512) {
        if (tid < W_) sc[tid] = w2v[tid];          // ws
        __syncthreads();
        int q = tid & 31, cw = tid >> 5;           // cw 0..15, 8 w each
        int bk0 = blockIdx.x * 32;
        int b = bk0 >> 11;
        int k = (bk0 & (K_ - 1)) + q;
        const float* xp = x + ((size_t)b * W_ + cw * 8) * K_ + k;
        float xv[8];
        float acc = 0.f;
#pragma unroll
        for (int w = 0; w < 8; ++w) {
            xv[w] = xp[(size_t)w * K_];
            acc += xv[w] * sc[cw * 8 + w];
        }
        sc[128 + cw * 33 + q] = acc;               // red[16][33]
        __syncthreads();
        if (tid < 32) {
            float s = 0.f;
#pragma unroll
            for (int cc = 0; cc < 16; ++cc) s += sc[128 + cc * 33 + tid];
            sc[656 + tid] = __expf(s);             // e1s; |u2| small, shift-invariant
        }
        __syncthreads();
        float e1q = sc[656 + q];
        short* xo = xbt + (((size_t)b * NC + (k >> 3)) * WX + cw * 8) * 8 + (k & 7);
#pragma unroll
        for (int w = 0; w < 8; ++w) xo[w * 8] = f2bf(xv[w] * e1q);
        if (tid < 32) {   // E1 column (w=128)
            int kk = (bk0 & (K_ - 1)) + tid;
            xbt[(((size_t)b * NC + (kk >> 3)) * WX + 128) * 8 + (kk & 7)] = f2bf(sc[656 + tid]);
        }
        if (tid >= 64 && tid < 124) {   // zero cols 129..143
            int id = tid - 64;
            int cl = id / 15, wz = 129 + id % 15;
            int c = ((bk0 & (K_ - 1)) >> 3) + cl;
            bf16x8 z = {0, 0, 0, 0, 0, 0, 0, 0};
            *(bf16x8*)(xbt + (((size_t)b * NC + c) * WX + wz) * 8) = z;
        }
    } else {
        int i0e = (int)(blockIdx.x - 512) * 4;
        {
            int r = tid >> 7, t128 = tid & 127;
            const float4* bp = (const float4*)(bias + (size_t)(i0e + r) * K_);
            float m = -1e30f;
#pragma unroll
            for (int s = 0; s < 4; ++s) {
                float4 v = bp[t128 + s * 128];
                m = fmaxf(m, fmaxf(fmaxf(v.x, v.y), fmaxf(v.z, v.w)));
            }
#pragma unroll
            for (int mm = 1; mm < 64; mm <<= 1) m = fmaxf(m, __shfl_xor(m, mm));
            if (lane == 0) sc[wid] = m;
        }
        __syncthreads();
        {
            int il = tid & 3, cg_ = tid >> 2;
            float mb = fmaxf(sc[il * 2], sc[il * 2 + 1]);
            int i = i0e + il;
            const float4* brow = (const float4*)(bias + (size_t)i * K_);
#pragma unroll
            for (int it = 0; it < 2; ++it) {
                int c = cg_ * 2 + it;
                float4 v0 = brow[c * 2];
                float4 v1 = brow[c * 2 + 1];
                bf16x8 o;
                o[0] = f2bf(__expf(v0.x - mb)); o[1] = f2bf(__expf(v0.y - mb));
                o[2] = f2bf(__expf(v0.z - mb)); o[3] = f2bf(__expf(v0.w - mb));
                o[4] = f2bf(__expf(v1.x - mb)); o[5] = f2bf(__expf(v1.y - mb));
                o[6] = f2bf(__expf(v1.z - mb)); o[7] = f2bf(__expf(v1.w - mb));
                *(bf16x8*)(e2t + ((size_t)c * K_ + i) * 8) = o;
            }
        }
    }
}

// ---------- k_gemm: LDS-staged B shared across m-waves ----------
// grid 256 x 1024 thr: b = blk&7 (XCD-pinned), i0 = (blk>>3)*64 (64 rows).
// 16 waves = 4 m-tiles (16 rows) x 4 j-quarters (512 j). Per jq, its 4 m-waves
// cooperatively stage each K=32 step's B (9 frags x 1KB) into a double-buffered
// LDS stream via global_load_lds (zero VGPR), then all consume via ds_read_b128.
// B fetched once per 64 rows -> 147 MB total (vs 295 r14). A reg-prefetched depth-1.
#define MF(a_, b_, c_) __builtin_amdgcn_mfma_f32_16x16x32_bf16(a_, b_, c_, 0, 0, 0)

#define GLLDS(gsrc, ldst) __builtin_amdgcn_global_load_lds(                      \
    (const u32 __attribute__((address_space(1)))*)(const void*)(gsrc),           \
    (u32 __attribute__((address_space(3)))*)(void*)(ldst), 16, 0, 0)

__global__ __launch_bounds__(1024, 4) void k_gemm(const short* __restrict__ e2t,
        const short* __restrict__ xbt, float* __restrict__ out) {
    __shared__ __align__(16) char Bb[73728];   // [jq][2 buf][9216]; aliased for reduce
    int blk  = blockIdx.x;
    int b    = blk & 7;                  // XCD round-robin -> same b per XCD
    int i0   = (blk >> 3) * 64;
    int tid  = threadIdx.x;
    int wid  = tid >> 6;
    int lane = tid & 63;
    int il   = lane & 15;
    int kg   = lane >> 4;
    int m    = wid & 3;                  // m-tile: rows i0 + m*16 ..
    int jq   = wid >> 2;                 // j-quarter: 512 j, 16 K-steps

    int i0r = i0 + m * 16;
    const short* eA = e2t + (((size_t)(jq * 64 + kg)) * K_ + i0r + il) * 8;
    size_t xbase = ((size_t)b * NC + jq * 64 + kg) * WX + il;   // + (s*4)*WX + f*16
    char* jbuf = Bb + jq * 18432;

    // stage step s into buffer bo (0/9216): wave handles frags f = m, m+4, m+8
#define STAGE(s_, bo_) do {                                                      \
    const short* _g = xbt + (xbase + (size_t)(s_) * 4 * WX) * 8;                 \
    char* _d = jbuf + (bo_);                                                     \
    for (int f = m; f < 9; f += 4)                                               \
        GLLDS(_g + f * 128, _d + f * 1024);                                      \
} while (0)

#define FA(dst_, s_) dst_ = *(const bf16x8*)(eA + (size_t)(s_) * 4 * K_ * 8)

    f32x4 q0{0,0,0,0}, q1{0,0,0,0}, q2{0,0,0,0}, q3{0,0,0,0}, q4{0,0,0,0},
          q5{0,0,0,0}, q6{0,0,0,0}, q7{0,0,0,0}, q8{0,0,0,0};

#define CONSUME(bo_, A_) do {                                                    \
    const char* _bp = jbuf + (bo_);                                              \
    bf16x8 b0 = *(const bf16x8*)(_bp +    0 + lane * 16);                        \
    bf16x8 b1 = *(const bf16x8*)(_bp + 1024 + lane * 16);                        \
    bf16x8 b2 = *(const bf16x8*)(_bp + 2048 + lane * 16);                        \
    bf16x8 b3 = *(const bf16x8*)(_bp + 3072 + lane * 16);                        \
    bf16x8 b4 = *(const bf16x8*)(_bp + 4096 + lane * 16);                        \
    bf16x8 b5 = *(const bf16x8*)(_bp + 5120 + lane * 16);                        \
    bf16x8 b6 = *(const bf16x8*)(_bp + 6144 + lane * 16);                        \
    bf16x8 b7 = *(const bf16x8*)(_bp + 7168 + lane * 16);                        \
    bf16x8 b8 = *(const bf16x8*)(_bp + 8192 + lane * 16);                        \
    __builtin_amdgcn_s_setprio(1);                                               \
    q0 = MF(A_, b0, q0); q1 = MF(A_, b1, q1); q2 = MF(A_, b2, q2);               \
    q3 = MF(A_, b3, q3); q4 = MF(A_, b4, q4); q5 = MF(A_, b5, q5);               \
    q6 = MF(A_, b6, q6); q7 = MF(A_, b7, q7); q8 = MF(A_, b8, q8);               \
    __builtin_amdgcn_s_setprio(0);                                               \
} while (0)

    bf16x8 AX, AY;
    STAGE(0, 0);
    FA(AX, 0);
    __syncthreads();                     // buf0 ready
    for (int s = 0; s < 16; s += 2) {
        STAGE(s + 1, 9216);              // in flight during consume(s)
        FA(AY, s + 1);
        CONSUME(0, AX);
        __syncthreads();                 // buf1 ready, buf0 free
        if (s + 2 < 16) { STAGE(s + 2, 0); FA(AX, s + 2); }
        CONSUME(9216, AY);
        __syncthreads();                 // buf0 ready (or loop exit)
    }

    // reduce over jq (4 -> 2 -> 1) in aliased LDS, then jq0 stores
    f32x4* R = (f32x4*)Bb;
#define DUMPQ(base_) do {                                                        \
    f32x4* _r = R + ((base_) + m * 9) * 64 + lane;                               \
    _r[0*64] = q0; _r[1*64] = q1; _r[2*64] = q2; _r[3*64] = q3; _r[4*64] = q4;   \
    _r[5*64] = q5; _r[6*64] = q6; _r[7*64] = q7; _r[8*64] = q8; } while (0)
#define GATHQ(base_) do {                                                        \
    f32x4* _r = R + ((base_) + m * 9) * 64 + lane;                               \
    q0 += _r[0*64]; q1 += _r[1*64]; q2 += _r[2*64]; q3 += _r[3*64];              \
    q4 += _r[4*64]; q5 += _r[5*64]; q6 += _r[6*64]; q7 += _r[7*64];              \
    q8 += _r[8*64]; } while (0)

    if (jq >= 2) DUMPQ((jq - 2) * 36);
    __syncthreads();
    if (jq < 2) GATHQ(jq * 36);
    __syncthreads();
    if (jq == 1) DUMPQ(0);
    __syncthreads();
    if (jq == 0) {
        GATHQ(0);
        // l for rows kg*4+r is q8[r] at lane kg*16 (w=128 column of X')
        float linv0 = 1.f / __shfl(q8[0], kg * 16);
        float linv1 = 1.f / __shfl(q8[1], kg * 16);
        float linv2 = 1.f / __shfl(q8[2], kg * 16);
        float linv3 = 1.f / __shfl(q8[3], kg * 16);
        float* ob = out + (size_t)b * W_ * K_ + i0r + kg * 4;
#define STQ(n_, q_) do {                                                         \
        float4 o;                                                                \
        o.x = 1.f / (1.f + __expf(-q_[0] * linv0));                              \
        o.y = 1.f / (1.f + __expf(-q_[1] * linv1));                              \
        o.z = 1.f / (1.f + __expf(-q_[2] * linv2));                              \
        o.w = 1.f / (1.f + __expf(-q_[3] * linv3));                              \
        *(float4*)(ob + (size_t)((n_) * 16 + il) * K_) = o; } while (0)
        STQ(0, q0); STQ(1, q1); STQ(2, q2); STQ(3, q3);
        STQ(4, q4); STQ(5, q5); STQ(6, q6); STQ(7, q7);
#undef STQ
    }
}

extern "C" void kernel_launch(void* const* d_in, const int* in_sizes, int n_in,
                              void* d_out, int out_size, void* d_ws, size_t ws_size,
                              hipStream_t stream) {
    const float* x     = (const float*)d_in[0];
    const float* W_lin = (const float*)d_in[1];
    // d_in[2] = b_lin: constant along softmax axis -> cancels, unused
    const float* a     = (const float*)d_in[3];
    const float* bias  = (const float*)d_in[4];
    float* out = (float*)d_out;

    float* w2v = (float*)d_ws;                    // 128 f32
    short* xbt = (short*)(w2v + 128);             // 8*256*144*8 bf16 = 4.72 MB
    short* e2t = xbt + (size_t)B_ * NC * WX * 8;  // 256*2048*8 bf16 = 8 MB

    k_w2v <<<128, 64, 0, stream>>>(W_lin, a, w2v);
    k_pe  <<<1024, 512, 0, stream>>>(x, w2v, bias, xbt, e2t);
    k_gemm<<<256, 1024, 0, stream>>>(e2t, xbt, out);
}

// Round 16
// 35.512 us; speedup vs baseline: 3.0376x; 1.1207x over previous
//
#include <hip/hip_runtime.h>
#include <hip/hip_bf16.h>

#define B_ 8
#define W_ 128
#define K_ 2048
#define D_ 256
#define WX 144            // padded w-dim: 128 x-cols + E1-col(128) + 15 zero cols
#define NC 256            // K/8 j-chunks

typedef __attribute__((ext_vector_type(8))) short bf16x8;
typedef __attribute__((ext_vector_type(4))) float f32x4;
typedef unsigned int u32;

static __device__ __forceinline__ short f2bf(float f) {
    unsigned int u = __float_as_uint(f);
    unsigned int r = (u + 0x7FFFu + ((u >> 16) & 1u)) >> 16;
    return (short)r;
}

// ---------- k_w2v ----------
__global__ void k_w2v(const float* __restrict__ W_lin, const float* __restrict__ a,
                      float* __restrict__ w2v) {
    int w = blockIdx.x, l = threadIdx.x;
    float4 rv = ((const float4*)(W_lin + (size_t)(W_ + w) * D_))[l];
    float4 av = ((const float4*)a)[l];
    float acc = rv.x * av.x + rv.y * av.y + rv.z * av.z + rv.w * av.w;
    for (int m = 1; m < 64; m <<= 1) acc += __shfl_xor(acc, m);
    if (l == 0) w2v[w] = acc;
}

// ---------- k_pe: heterogeneous grid (1024 blocks x 512 thr) [proven, unchanged]
__global__ __launch_bounds__(512) void k_pe(const float* __restrict__ x,
        const float* __restrict__ w2v, const float* __restrict__ bias,
        short* __restrict__ xbt, short* __restrict__ e2t) {
    __shared__ float sc[696];
    int tid = threadIdx.x;
    int wid = tid >> 6;
    int lane = tid & 63;

    if (blockIdx.x < 512) {
        if (tid < W_) sc[tid] = w2v[tid];          // ws
        __syncthreads();
        int q = tid & 31, cw = tid >> 5;           // cw 0..15, 8 w each
        int bk0 = blockIdx.x * 32;
        int b = bk0 >> 11;
        int k = (bk0 & (K_ - 1)) + q;
        const float* xp = x + ((size_t)b * W_ + cw * 8) * K_ + k;
        float xv[8];
        float acc = 0.f;
#pragma unroll
        for (int w = 0; w < 8; ++w) {
            xv[w] = xp[(size_t)w * K_];
            acc += xv[w] * sc[cw * 8 + w];
        }
        sc[128 + cw * 33 + q] = acc;               // red[16][33]
        __syncthreads();
        if (tid < 32) {
            float s = 0.f;
#pragma unroll
            for (int cc = 0; cc < 16; ++cc) s += sc[128 + cc * 33 + tid];
            sc[656 + tid] = __expf(s);             // e1s; |u2| small, shift-invariant
        }
        __syncthreads();
        float e1q = sc[656 + q];
        short* xo = xbt + (((size_t)b * NC + (k >> 3)) * WX + cw * 8) * 8 + (k & 7);
#pragma unroll
        for (int w = 0; w < 8; ++w) xo[w * 8] = f2bf(xv[w] * e1q);
        if (tid < 32) {   // E1 column (w=128)
            int kk = (bk0 & (K_ - 1)) + tid;
            xbt[(((size_t)b * NC + (kk >> 3)) * WX + 128) * 8 + (kk & 7)] = f2bf(sc[656 + tid]);
        }
        if (tid >= 64 && tid < 124) {   // zero cols 129..143
            int id = tid - 64;
            int cl = id / 15, wz = 129 + id % 15;
            int c = ((bk0 & (K_ - 1)) >> 3) + cl;
            bf16x8 z = {0, 0, 0, 0, 0, 0, 0, 0};
            *(bf16x8*)(xbt + (((size_t)b * NC + c) * WX + wz) * 8) = z;
        }
    } else {
        int i0e = (int)(blockIdx.x - 512) * 4;
        {
            int r = tid >> 7, t128 = tid & 127;
            const float4* bp = (const float4*)(bias + (size_t)(i0e + r) * K_);
            float m = -1e30f;
#pragma unroll
            for (int s = 0; s < 4; ++s) {
                float4 v = bp[t128 + s * 128];
                m = fmaxf(m, fmaxf(fmaxf(v.x, v.y), fmaxf(v.z, v.w)));
            }
#pragma unroll
            for (int mm = 1; mm < 64; mm <<= 1) m = fmaxf(m, __shfl_xor(m, mm));
            if (lane == 0) sc[wid] = m;
        }
        __syncthreads();
        {
            int il = tid & 3, cg_ = tid >> 2;
            float mb = fmaxf(sc[il * 2], sc[il * 2 + 1]);
            int i = i0e + il;
            const float4* brow = (const float4*)(bias + (size_t)i * K_);
#pragma unroll
            for (int it = 0; it < 2; ++it) {
                int c = cg_ * 2 + it;
                float4 v0 = brow[c * 2];
                float4 v1 = brow[c * 2 + 1];
                bf16x8 o;
                o[0] = f2bf(__expf(v0.x - mb)); o[1] = f2bf(__expf(v0.y - mb));
                o[2] = f2bf(__expf(v0.z - mb)); o[3] = f2bf(__expf(v0.w - mb));
                o[4] = f2bf(__expf(v1.x - mb)); o[5] = f2bf(__expf(v1.y - mb));
                o[6] = f2bf(__expf(v1.z - mb)); o[7] = f2bf(__expf(v1.w - mb));
                *(bf16x8*)(e2t + ((size_t)c * K_ + i) * 8) = o;
            }
        }
    }
}

// ---------- k_gemm: LDS-staged B, 4-deep ring, counted vmcnt + raw barriers (T3/T4)
// grid 256 x 1024 thr: b = blk&7 (XCD-pinned), i0 = (blk>>3)*64.
// 16 waves = 4 m-tiles x 4 j-quarters. Per jq: 4 ring buffers x 9KB (144KB LDS).
// Step s: issue A[s+2] + STAGE(s+2) -> vmcnt(N, never 0 in main loop) -> raw
// s_barrier -> consume s. Slot (s+2)&3 last consumed at s-2, which precedes
// barrier s-1 -> collective barrier makes the overwrite safe.
#define MF(a_, b_, c_) __builtin_amdgcn_mfma_f32_16x16x32_bf16(a_, b_, c_, 0, 0, 0)

#define GLLDS(gsrc, ldst) __builtin_amdgcn_global_load_lds(                      \
    (const u32 __attribute__((address_space(1)))*)(const void*)(gsrc),           \
    (u32 __attribute__((address_space(3)))*)(void*)(ldst), 16, 0, 0)

#define WAITV(n_) asm volatile("s_waitcnt vmcnt(" #n_ ")" ::: "memory")
#define BARR __builtin_amdgcn_s_barrier()

__global__ __launch_bounds__(1024, 4) void k_gemm(const short* __restrict__ e2t,
        const short* __restrict__ xbt, float* __restrict__ out) {
    __shared__ __align__(16) char Bb[147456];   // [jq][4 ring][9216]; aliased for reduce
    int blk  = blockIdx.x;
    int b    = blk & 7;                  // XCD round-robin -> same b per XCD
    int i0   = (blk >> 3) * 64;
    int tid  = threadIdx.x;
    int wid  = tid >> 6;
    int lane = tid & 63;
    int il   = lane & 15;
    int kg   = lane >> 4;
    int m    = wid & 3;                  // m-tile: rows i0 + m*16 ..
    int jq   = wid >> 2;                 // j-quarter: 512 j, 16 K-steps

    int i0r = i0 + m * 16;
    const short* eA = e2t + (((size_t)(jq * 64 + kg)) * K_ + i0r + il) * 8;
    size_t xbase = ((size_t)b * NC + jq * 64 + kg) * WX + il;
    char* jbuf = Bb + jq * 36864;

#define STG(s_) do {                                                             \
    const short* _g = xbt + (xbase + (size_t)(s_) * 4 * WX) * 8;                 \
    char* _d = jbuf + ((s_) & 3) * 9216;                                         \
    for (int f = m; f < 9; f += 4)                                               \
        GLLDS(_g + f * 128, _d + f * 1024);                                      \
} while (0)

#define FAix(sl_, s_) Ar##sl_ = *(const bf16x8*)(eA + (size_t)(s_) * 4 * K_ * 8)

    f32x4 q0{0,0,0,0}, q1{0,0,0,0}, q2{0,0,0,0}, q3{0,0,0,0}, q4{0,0,0,0},
          q5{0,0,0,0}, q6{0,0,0,0}, q7{0,0,0,0}, q8{0,0,0,0};

#define CONS(s_, sl_) do {                                                       \
    const char* _bp = jbuf + ((s_) & 3) * 9216;                                  \
    bf16x8 b0 = *(const bf16x8*)(_bp +    0 + lane * 16);                        \
    bf16x8 b1 = *(const bf16x8*)(_bp + 1024 + lane * 16);                        \
    bf16x8 b2 = *(const bf16x8*)(_bp + 2048 + lane * 16);                        \
    bf16x8 b3 = *(const bf16x8*)(_bp + 3072 + lane * 16);                        \
    bf16x8 b4 = *(const bf16x8*)(_bp + 4096 + lane * 16);                        \
    bf16x8 b5 = *(const bf16x8*)(_bp + 5120 + lane * 16);                        \
    bf16x8 b6 = *(const bf16x8*)(_bp + 6144 + lane * 16);                        \
    bf16x8 b7 = *(const bf16x8*)(_bp + 7168 + lane * 16);                        \
    bf16x8 b8 = *(const bf16x8*)(_bp + 8192 + lane * 16);                        \
    __builtin_amdgcn_s_setprio(1);                                               \
    q0 = MF(Ar##sl_, b0, q0); q1 = MF(Ar##sl_, b1, q1); q2 = MF(Ar##sl_, b2, q2);\
    q3 = MF(Ar##sl_, b3, q3); q4 = MF(Ar##sl_, b4, q4); q5 = MF(Ar##sl_, b5, q5);\
    q6 = MF(Ar##sl_, b6, q6); q7 = MF(Ar##sl_, b7, q7); q8 = MF(Ar##sl_, b8, q8);\
    __builtin_amdgcn_s_setprio(0);                                               \
} while (0)

// main-loop step: issue step s2 (= s+2), counted wait, raw barrier, consume s
#define STEP(s_, sl_, s2_, sl2_) do {                                            \
    FAix(sl2_, s2_); STG(s2_);                                                   \
    if (m == 0) WAITV(8); else WAITV(6);                                         \
    BARR;                                                                        \
    CONS(s_, sl_);                                                               \
} while (0)

    bf16x8 Ar0, Ar1, Ar2, Ar3;
    // prologue: stages 0,1 in flight
    FAix(0, 0); STG(0);
    FAix(1, 1); STG(1);

    STEP(0, 0, 2, 2);   STEP(1, 1, 3, 3);
    STEP(2, 2, 4, 0);   STEP(3, 3, 5, 1);
    STEP(4, 0, 6, 2);   STEP(5, 1, 7, 3);
    STEP(6, 2, 8, 0);   STEP(7, 3, 9, 1);
    STEP(8, 0, 10, 2);  STEP(9, 1, 11, 3);
    STEP(10, 2, 12, 0); STEP(11, 3, 13, 1);
    STEP(12, 0, 14, 2); STEP(13, 1, 15, 3);
    // tail: only stage 15 (+A15) outstanding, then nothing
    if (m == 0) WAITV(4); else WAITV(3);
    BARR;
    CONS(14, 2);
    WAITV(0);
    BARR;
    CONS(15, 3);

    __syncthreads();                     // full drain before LDS re-use

    // reduce over jq (4 -> 2 -> 1) in aliased LDS, then jq0 stores
    f32x4* R = (f32x4*)Bb;
#define DUMPQ(base_) do {                                                        \
    f32x4* _r = R + ((base_) + m * 9) * 64 + lane;                               \
    _r[0*64] = q0; _r[1*64] = q1; _r[2*64] = q2; _r[3*64] = q3; _r[4*64] = q4;   \
    _r[5*64] = q5; _r[6*64] = q6; _r[7*64] = q7; _r[8*64] = q8; } while (0)
#define GATHQ(base_) do {                                                        \
    f32x4* _r = R + ((base_) + m * 9) * 64 + lane;                               \
    q0 += _r[0*64]; q1 += _r[1*64]; q2 += _r[2*64]; q3 += _r[3*64];              \
    q4 += _r[4*64]; q5 += _r[5*64]; q6 += _r[6*64]; q7 += _r[7*64];              \
    q8 += _r[8*64]; } while (0)

    if (jq >= 2) DUMPQ((jq - 2) * 36);
    __syncthreads();
    if (jq < 2) GATHQ(jq * 36);
    __syncthreads();
    if (jq == 1) DUMPQ(0);
    __syncthreads();
    if (jq == 0) {
        GATHQ(0);
        // l for rows kg*4+r is q8[r] at lane kg*16 (w=128 column of X')
        float linv0 = 1.f / __shfl(q8[0], kg * 16);
        float linv1 = 1.f / __shfl(q8[1], kg * 16);
        float linv2 = 1.f / __shfl(q8[2], kg * 16);
        float linv3 = 1.f / __shfl(q8[3], kg * 16);
        float* ob = out + (size_t)b * W_ * K_ + i0r + kg * 4;
#define STQ(n_, q_) do {                                                         \
        float4 o;                                                                \
        o.x = 1.f / (1.f + __expf(-q_[0] * linv0));                              \
        o.y = 1.f / (1.f + __expf(-q_[1] * linv1));                              \
        o.z = 1.f / (1.f + __expf(-q_[2] * linv2));                              \
        o.w = 1.f / (1.f + __expf(-q_[3] * linv3));                              \
        *(float4*)(ob + (size_t)((n_) * 16 + il) * K_) = o; } while (0)
        STQ(0, q0); STQ(1, q1); STQ(2, q2); STQ(3, q3);
        STQ(4, q4); STQ(5, q5); STQ(6, q6); STQ(7, q7);
#undef STQ
    }
}

extern "C" void kernel_launch(void* const* d_in, const int* in_sizes, int n_in,
                              void* d_out, int out_size, void* d_ws, size_t ws_size,
                              hipStream_t stream) {
    const float* x     = (const float*)d_in[0];
    const float* W_lin = (const float*)d_in[1];
    // d_in[2] = b_lin: constant along softmax axis -> cancels, unused
    const float* a     = (const float*)d_in[3];
    const float* bias  = (const float*)d_in[4];
    float* out = (float*)d_out;

    float* w2v = (float*)d_ws;                    // 128 f32
    short* xbt = (short*)(w2v + 128);             // 8*256*144*8 bf16 = 4.72 MB
    short* e2t = xbt + (size_t)B_ * NC * WX * 8;  // 256*2048*8 bf16 = 8 MB

    k_w2v <<<128, 64, 0, stream>>>(W_lin, a, w2v);
    k_pe  <<<1024, 512, 0, stream>>>(x, w2v, bias, xbt, e2t);
    k_gemm<<<256, 1024, 0, stream>>>(e2t, xbt, out);
}

// Round 17
// 34.315 us; speedup vs baseline: 3.1436x; 1.0349x over previous
//
#include <hip/hip_runtime.h>
#include <hip/hip_bf16.h>

#define B_ 8
#define W_ 128
#define K_ 2048
#define D_ 256
#define WX 144            // padded w-dim: 128 x-cols + E1-col(128) + 15 zero cols
#define NC 256            // K/8 j-chunks

typedef __attribute__((ext_vector_type(8))) short bf16x8;
typedef __attribute__((ext_vector_type(4))) float f32x4;
typedef unsigned int u32;

static __device__ __forceinline__ short f2bf(float f) {
    unsigned int u = __float_as_uint(f);
    unsigned int r = (u + 0x7FFFu + ((u >> 16) & 1u)) >> 16;
    return (short)r;
}

// ---------- k_w2v ----------
__global__ void k_w2v(const float* __restrict__ W_lin, const float* __restrict__ a,
                      float* __restrict__ w2v) {
    int w = blockIdx.x, l = threadIdx.x;
    float4 rv = ((const float4*)(W_lin + (size_t)(W_ + w) * D_))[l];
    float4 av = ((const float4*)a)[l];
    float acc = rv.x * av.x + rv.y * av.y + rv.z * av.z + rv.w * av.w;
    for (int m = 1; m < 64; m <<= 1) acc += __shfl_xor(acc, m);
    if (l == 0) w2v[w] = acc;
}

// ---------- k_pe: heterogeneous grid (1024 blocks x 512 thr)
// blocks 0..511  : prep (unchanged, proven)
// blocks 512..1023: e2 SINGLE-PASS -> bias held in 16 regs; rowmax via shfl class
//                   reduce + 8-wave LDS combine; exp+pack+write from regs.
__global__ __launch_bounds__(512) void k_pe(const float* __restrict__ x,
        const float* __restrict__ w2v, const float* __restrict__ bias,
        short* __restrict__ xbt, short* __restrict__ e2t) {
    __shared__ float sc[696];
    int tid = threadIdx.x;
    int wid = tid >> 6;
    int lane = tid & 63;

    if (blockIdx.x < 512) {
        if (tid < W_) sc[tid] = w2v[tid];          // ws
        __syncthreads();
        int q = tid & 31, cw = tid >> 5;           // cw 0..15, 8 w each
        int bk0 = blockIdx.x * 32;
        int b = bk0 >> 11;
        int k = (bk0 & (K_ - 1)) + q;
        const float* xp = x + ((size_t)b * W_ + cw * 8) * K_ + k;
        float xv[8];
        float acc = 0.f;
#pragma unroll
        for (int w = 0; w < 8; ++w) {
            xv[w] = xp[(size_t)w * K_];
            acc += xv[w] * sc[cw * 8 + w];
        }
        sc[128 + cw * 33 + q] = acc;               // red[16][33]
        __syncthreads();
        if (tid < 32) {
            float s = 0.f;
#pragma unroll
            for (int cc = 0; cc < 16; ++cc) s += sc[128 + cc * 33 + tid];
            sc[656 + tid] = __expf(s);             // e1s; |u2| small, shift-invariant
        }
        __syncthreads();
        float e1q = sc[656 + q];
        short* xo = xbt + (((size_t)b * NC + (k >> 3)) * WX + cw * 8) * 8 + (k & 7);
#pragma unroll
        for (int w = 0; w < 8; ++w) xo[w * 8] = f2bf(xv[w] * e1q);
        if (tid < 32) {   // E1 column (w=128)
            int kk = (bk0 & (K_ - 1)) + tid;
            xbt[(((size_t)b * NC + (kk >> 3)) * WX + 128) * 8 + (kk & 7)] = f2bf(sc[656 + tid]);
        }
        if (tid >= 64 && tid < 124) {   // zero cols 129..143
            int id = tid - 64;
            int cl = id / 15, wz = 129 + id % 15;
            int c = ((bk0 & (K_ - 1)) >> 3) + cl;
            bf16x8 z = {0, 0, 0, 0, 0, 0, 0, 0};
            *(bf16x8*)(xbt + (((size_t)b * NC + c) * WX + wz) * 8) = z;
        }
    } else {
        // ---- e2 single-pass: 4 rows/block; thread (il=tid&3, cg=tid>>2) holds
        // j = cg*16 .. cg*16+15 of row i0e+il in 4 float4 regs.
        int i0e = (int)(blockIdx.x - 512) * 4;
        int il = tid & 3, cg = tid >> 2;           // cg 0..127
        const float4* brow = (const float4*)(bias + (size_t)(i0e + il) * K_);
        float4 v0 = brow[cg * 4 + 0];
        float4 v1 = brow[cg * 4 + 1];
        float4 v2 = brow[cg * 4 + 2];
        float4 v3 = brow[cg * 4 + 3];
        float m = fmaxf(fmaxf(fmaxf(v0.x, v0.y), fmaxf(v0.z, v0.w)),
                        fmaxf(fmaxf(v1.x, v1.y), fmaxf(v1.z, v1.w)));
        m = fmaxf(m, fmaxf(fmaxf(fmaxf(v2.x, v2.y), fmaxf(v2.z, v2.w)),
                           fmaxf(fmaxf(v3.x, v3.y), fmaxf(v3.z, v3.w))));
        // reduce across lanes of the same il class (stride-4 lanes)
#pragma unroll
        for (int mm = 4; mm < 64; mm <<= 1) m = fmaxf(m, __shfl_xor(m, mm));
        if (lane < 4) sc[wid * 4 + lane] = m;      // lane==il for lanes 0..3
        __syncthreads();
        float mb = sc[il];
#pragma unroll
        for (int w = 1; w < 8; ++w) mb = fmaxf(mb, sc[w * 4 + il]);
        // exp + pack from registers; write i-inner (64B runs)
        bf16x8 o0, o1;
        o0[0] = f2bf(__expf(v0.x - mb)); o0[1] = f2bf(__expf(v0.y - mb));
        o0[2] = f2bf(__expf(v0.z - mb)); o0[3] = f2bf(__expf(v0.w - mb));
        o0[4] = f2bf(__expf(v1.x - mb)); o0[5] = f2bf(__expf(v1.y - mb));
        o0[6] = f2bf(__expf(v1.z - mb)); o0[7] = f2bf(__expf(v1.w - mb));
        o1[0] = f2bf(__expf(v2.x - mb)); o1[1] = f2bf(__expf(v2.y - mb));
        o1[2] = f2bf(__expf(v2.z - mb)); o1[3] = f2bf(__expf(v2.w - mb));
        o1[4] = f2bf(__expf(v3.x - mb)); o1[5] = f2bf(__expf(v3.y - mb));
        o1[6] = f2bf(__expf(v3.z - mb)); o1[7] = f2bf(__expf(v3.w - mb));
        int i = i0e + il;
        *(bf16x8*)(e2t + ((size_t)(cg * 2) * K_ + i) * 8)     = o0;
        *(bf16x8*)(e2t + ((size_t)(cg * 2 + 1) * K_ + i) * 8) = o1;
    }
}

// ---------- k_gemm: LDS-staged B, 4-deep ring, counted vmcnt + raw barriers (T3/T4)
// [byte-identical to r16 — proven 35.5 µs config]
#define MF(a_, b_, c_) __builtin_amdgcn_mfma_f32_16x16x32_bf16(a_, b_, c_, 0, 0, 0)

#define GLLDS(gsrc, ldst) __builtin_amdgcn_global_load_lds(                      \
    (const u32 __attribute__((address_space(1)))*)(const void*)(gsrc),           \
    (u32 __attribute__((address_space(3)))*)(void*)(ldst), 16, 0, 0)

#define WAITV(n_) asm volatile("s_waitcnt vmcnt(" #n_ ")" ::: "memory")
#define BARR __builtin_amdgcn_s_barrier()

__global__ __launch_bounds__(1024, 4) void k_gemm(const short* __restrict__ e2t,
        const short* __restrict__ xbt, float* __restrict__ out) {
    __shared__ __align__(16) char Bb[147456];   // [jq][4 ring][9216]; aliased for reduce
    int blk  = blockIdx.x;
    int b    = blk & 7;                  // XCD round-robin -> same b per XCD
    int i0   = (blk >> 3) * 64;
    int tid  = threadIdx.x;
    int wid  = tid >> 6;
    int lane = tid & 63;
    int il   = lane & 15;
    int kg   = lane >> 4;
    int m    = wid & 3;                  // m-tile: rows i0 + m*16 ..
    int jq   = wid >> 2;                 // j-quarter: 512 j, 16 K-steps

    int i0r = i0 + m * 16;
    const short* eA = e2t + (((size_t)(jq * 64 + kg)) * K_ + i0r + il) * 8;
    size_t xbase = ((size_t)b * NC + jq * 64 + kg) * WX + il;
    char* jbuf = Bb + jq * 36864;

#define STG(s_) do {                                                             \
    const short* _g = xbt + (xbase + (size_t)(s_) * 4 * WX) * 8;                 \
    char* _d = jbuf + ((s_) & 3) * 9216;                                         \
    for (int f = m; f < 9; f += 4)                                               \
        GLLDS(_g + f * 128, _d + f * 1024);                                      \
} while (0)

#define FAix(sl_, s_) Ar##sl_ = *(const bf16x8*)(eA + (size_t)(s_) * 4 * K_ * 8)

    f32x4 q0{0,0,0,0}, q1{0,0,0,0}, q2{0,0,0,0}, q3{0,0,0,0}, q4{0,0,0,0},
          q5{0,0,0,0}, q6{0,0,0,0}, q7{0,0,0,0}, q8{0,0,0,0};

#define CONS(s_, sl_) do {                                                       \
    const char* _bp = jbuf + ((s_) & 3) * 9216;                                  \
    bf16x8 b0 = *(const bf16x8*)(_bp +    0 + lane * 16);                        \
    bf16x8 b1 = *(const bf16x8*)(_bp + 1024 + lane * 16);                        \
    bf16x8 b2 = *(const bf16x8*)(_bp + 2048 + lane * 16);                        \
    bf16x8 b3 = *(const bf16x8*)(_bp + 3072 + lane * 16);                        \
    bf16x8 b4 = *(const bf16x8*)(_bp + 4096 + lane * 16);                        \
    bf16x8 b5 = *(const bf16x8*)(_bp + 5120 + lane * 16);                        \
    bf16x8 b6 = *(const bf16x8*)(_bp + 6144 + lane * 16);                        \
    bf16x8 b7 = *(const bf16x8*)(_bp + 7168 + lane * 16);                        \
    bf16x8 b8 = *(const bf16x8*)(_bp + 8192 + lane * 16);                        \
    __builtin_amdgcn_s_setprio(1);                                               \
    q0 = MF(Ar##sl_, b0, q0); q1 = MF(Ar##sl_, b1, q1); q2 = MF(Ar##sl_, b2, q2);\
    q3 = MF(Ar##sl_, b3, q3); q4 = MF(Ar##sl_, b4, q4); q5 = MF(Ar##sl_, b5, q5);\
    q6 = MF(Ar##sl_, b6, q6); q7 = MF(Ar##sl_, b7, q7); q8 = MF(Ar##sl_, b8, q8);\
    __builtin_amdgcn_s_setprio(0);                                               \
} while (0)

#define STEP(s_, sl_, s2_, sl2_) do {                                            \
    FAix(sl2_, s2_); STG(s2_);                                                   \
    if (m == 0) WAITV(8); else WAITV(6);                                         \
    BARR;                                                                        \
    CONS(s_, sl_);                                                               \
} while (0)

    bf16x8 Ar0, Ar1, Ar2, Ar3;
    FAix(0, 0); STG(0);
    FAix(1, 1); STG(1);

    STEP(0, 0, 2, 2);   STEP(1, 1, 3, 3);
    STEP(2, 2, 4, 0);   STEP(3, 3, 5, 1);
    STEP(4, 0, 6, 2);   STEP(5, 1, 7, 3);
    STEP(6, 2, 8, 0);   STEP(7, 3, 9, 1);
    STEP(8, 0, 10, 2);  STEP(9, 1, 11, 3);
    STEP(10, 2, 12, 0); STEP(11, 3, 13, 1);
    STEP(12, 0, 14, 2); STEP(13, 1, 15, 3);
    if (m == 0) WAITV(4); else WAITV(3);
    BARR;
    CONS(14, 2);
    WAITV(0);
    BARR;
    CONS(15, 3);

    __syncthreads();

    f32x4* R = (f32x4*)Bb;
#define DUMPQ(base_) do {                                                        \
    f32x4* _r = R + ((base_) + m * 9) * 64 + lane;                               \
    _r[0*64] = q0; _r[1*64] = q1; _r[2*64] = q2; _r[3*64] = q3; _r[4*64] = q4;   \
    _r[5*64] = q5; _r[6*64] = q6; _r[7*64] = q7; _r[8*64] = q8; } while (0)
#define GATHQ(base_) do {                                                        \
    f32x4* _r = R + ((base_) + m * 9) * 64 + lane;                               \
    q0 += _r[0*64]; q1 += _r[1*64]; q2 += _r[2*64]; q3 += _r[3*64];              \
    q4 += _r[4*64]; q5 += _r[5*64]; q6 += _r[6*64]; q7 += _r[7*64];              \
    q8 += _r[8*64]; } while (0)

    if (jq >= 2) DUMPQ((jq - 2) * 36);
    __syncthreads();
    if (jq < 2) GATHQ(jq * 36);
    __syncthreads();
    if (jq == 1) DUMPQ(0);
    __syncthreads();
    if (jq == 0) {
        GATHQ(0);
        float linv0 = 1.f / __shfl(q8[0], kg * 16);
        float linv1 = 1.f / __shfl(q8[1], kg * 16);
        float linv2 = 1.f / __shfl(q8[2], kg * 16);
        float linv3 = 1.f / __shfl(q8[3], kg * 16);
        float* ob = out + (size_t)b * W_ * K_ + i0r + kg * 4;
#define STQ(n_, q_) do {                                                         \
        float4 o;                                                                \
        o.x = 1.f / (1.f + __expf(-q_[0] * linv0));                              \
        o.y = 1.f / (1.f + __expf(-q_[1] * linv1));                              \
        o.z = 1.f / (1.f + __expf(-q_[2] * linv2));                              \
        o.w = 1.f / (1.f + __expf(-q_[3] * linv3));                              \
        *(float4*)(ob + (size_t)((n_) * 16 + il) * K_) = o; } while (0)
        STQ(0, q0); STQ(1, q1); STQ(2, q2); STQ(3, q3);
        STQ(4, q4); STQ(5, q5); STQ(6, q6); STQ(7, q7);
#undef STQ
    }
}

extern "C" void kernel_launch(void* const* d_in, const int* in_sizes, int n_in,
                              void* d_out, int out_size, void* d_ws, size_t ws_size,
                              hipStream_t stream) {
    const float* x     = (const float*)d_in[0];
    const float* W_lin = (const float*)d_in[1];
    // d_in[2] = b_lin: constant along softmax axis -> cancels, unused
    const float* a     = (const float*)d_in[3];
    const float* bias  = (const float*)d_in[4];
    float* out = (float*)d_out;

    float* w2v = (float*)d_ws;                    // 128 f32
    short* xbt = (short*)(w2v + 128);             // 8*256*144*8 bf16 = 4.72 MB
    short* e2t = xbt + (size_t)B_ * NC * WX * 8;  // 256*2048*8 bf16 = 8 MB

    k_w2v <<<128, 64, 0, stream>>>(W_lin, a, w2v);
    k_pe  <<<1024, 512, 0, stream>>>(x, w2v, bias, xbt, e2t);
    k_gemm<<<256, 1024, 0, stream>>>(e2t, xbt, out);
}